// Round 5
// baseline (172.635 us; speedup 1.0000x reference)
//
#include <hip/hip_runtime.h>

#define BATCH 64
#define MGT 300
#define NCLS 20
#define IMG 480.0f

#define N0 (BATCH * 3 * 60 * 60)   // 691200 cells
#define N1 (BATCH * 3 * 30 * 30)   // 172800
#define N2 (BATCH * 3 * 15 * 15)   //  43200
#define NTOT (N0 + N1 + N2)        // 907200

#define F1 (N0 * 25 / 4)           // float4 counts
#define F2 (N1 * 25 / 4)
#define F3 (N2 * 25 / 4)
#define FT (F1 + F2 + F3)          // 5,670,000

#define MAIN_BLOCKS 2048           // 8 blocks/CU -> 32 waves/CU

typedef float f32x4 __attribute__((ext_vector_type(4)));  // native vec for nontemporal builtin

// Anchors: s0 (10,13),(16,30),(33,23); s1 (30,61),(62,45),(59,119); s2 (116,90),(156,198),(373,326)
__constant__ float c_aw[3][3] = {{10.f, 16.f, 33.f}, {30.f, 62.f, 59.f}, {116.f, 156.f, 373.f}};
__constant__ float c_ah[3][3] = {{13.f, 30.f, 23.f}, {61.f, 45.f, 119.f}, {90.f, 198.f, 326.f}};

__device__ __forceinline__ float wave_red(float v) {
    #pragma unroll
    for (int o = 32; o > 0; o >>= 1) v += __shfl_down(v, o, 64);
    return v;
}

// One thread per (b,m) GT: best anchor per scale; atomicMax(m) = last-write-wins scatter.
__global__ void assign_kernel(const float* __restrict__ gt,
                              int* __restrict__ win0, int* __restrict__ win1, int* __restrict__ win2) {
    int t = blockIdx.x * blockDim.x + threadIdx.x;
    if (t >= BATCH * MGT) return;
    int b = t / MGT;
    int m = t - b * MGT;
    const float* g = gt + (size_t)t * 25;
    if (!(g[4] > 0.5f)) return;
    float mx = g[0], my = g[1];
    float w = g[2] * IMG, h = g[3] * IMG;
    float wh = w * h;

    const int Gs[3] = {60, 30, 15};
    int* wins[3] = {win0, win1, win2};
    #pragma unroll
    for (int s = 0; s < 3; ++s) {
        int G = Gs[s];
        int gx = min(max((int)floorf(mx * (float)G), 0), G - 1);
        int gy = min(max((int)floorf(my * (float)G), 0), G - 1);
        float bestR = -1.0f;
        int best = 0;
        #pragma unroll
        for (int a = 0; a < 3; ++a) {
            float aw = c_aw[s][a], ah = c_ah[s][a];
            float inter = fminf(w, aw) * fminf(h, ah);
            float uni = wh + aw * ah - inter;
            float r = inter / (uni + 1e-16f);
            if (r > bestR) { bestR = r; best = a; }  // strict > : argmax first-wins
        }
        int cell = ((b * 3 + best) * G + gy) * G + gx;
        atomicMax(&wins[s][cell], m);
    }
}

// Winner cells only (~3%): coord/obj/cls + noObj correction. Compile-time G
// (R3 lesson: runtime G div/mod chains in the hot sweep).
template <int G, int S>
__device__ __forceinline__ void winner_sweep(const float* __restrict__ pred,
                                             const float* __restrict__ gt,
                                             const int* __restrict__ win,
                                             float& coord, float& objL, float& noObjC, float& clsL) {
    const int n = BATCH * 3 * G * G;
    for (int c = blockIdx.x * blockDim.x + threadIdx.x; c < n; c += gridDim.x * blockDim.x) {
        int m = win[c];
        if (m < 0) continue;
        const float* p = pred + (size_t)c * 25;
        float pconf = p[4];
        // stream phase added -lq for this cell; true noObj term is 0 -> add it back
        float lq = (pconf < 1.0f) ? fmaxf(logf(1.0f - pconf), -100.0f) : -100.0f;
        noObjC += lq;

        int gx = c % G;
        int t1 = c / G;
        int gy = t1 % G;
        int t2 = t1 / G;
        int a = t2 % 3;
        int b = t2 / 3;
        const float* g = gt + ((size_t)b * MGT + m) * 25;
        float w = g[2] * IMG, h = g[3] * IMG;
        float tx = g[0] * (float)G - (float)gx;
        float ty = g[1] * (float)G - (float)gy;
        float tw = logf(w / c_aw[S][a] + 1e-16f);
        float th = logf(h / c_ah[S][a] + 1e-16f);
        float dx = p[0] - tx, dy = p[1] - ty, dw = p[2] - tw, dh = p[3] - th;
        coord += dx * dx + dy * dy + dw * dw + dh * dh;
        float lp = (pconf > 0.0f) ? fmaxf(logf(pconf), -100.0f) : -100.0f;
        objL -= lp;
        #pragma unroll
        for (int k = 0; k < NCLS; ++k) {
            float pc = p[5 + k], tc = g[5 + k];
            float lpk = (pc > 0.0f) ? fmaxf(logf(pc), -100.0f) : -100.0f;
            float lqk = (pc < 1.0f) ? fmaxf(logf(1.0f - pc), -100.0f) : -100.0f;
            clsL -= tc * lpk + (1.0f - tc) * lqk;
        }
    }
}

// Phase A: coalesced nontemporal stream of ALL pred floats; extract conf
// ((idx mod 25)==4) in-register, accumulate bce(conf,0) for every cell.
// Phase B: winner sweeps (no inter-phase dependency; assign ran earlier).
__global__ __launch_bounds__(256) void main_kernel(
        const f32x4* __restrict__ p1v, const f32x4* __restrict__ p2v, const f32x4* __restrict__ p3v,
        const float* __restrict__ p1, const float* __restrict__ p2, const float* __restrict__ p3,
        const float* __restrict__ gt,
        const int* __restrict__ win0, const int* __restrict__ win1, const int* __restrict__ win2,
        float* __restrict__ partials) {
    float noObj = 0.f;
    const int stride = gridDim.x * blockDim.x;

    auto process = [&](int i) {
        const f32x4* base; int li;
        if (i < F1)           { base = p1v; li = i; }
        else if (i < F1 + F2) { base = p2v; li = i - F1; }
        else                  { base = p3v; li = i - F1 - F2; }
        f32x4 v = __builtin_nontemporal_load(&base[li]);
        unsigned r = (4u * (unsigned)li) % 25u;   // magic-mul (const divisor)
        unsigned j0 = (29u - r) % 25u;            // (4 - r) mod 25
        if (j0 < 4u) {                            // this float4 holds one conf
            float p = v[j0];
            float lq = (p < 1.0f) ? fmaxf(logf(1.0f - p), -100.0f) : -100.0f;
            noObj -= lq;
        }
    };

    int i = blockIdx.x * blockDim.x + threadIdx.x;
    // 2x unrolled: two independent loads in flight per iteration
    for (; i + stride < FT; i += 2 * stride) {
        process(i);
        process(i + stride);
    }
    if (i < FT) process(i);

    float coord = 0.f, objL = 0.f, noObjC = 0.f, clsL = 0.f;
    winner_sweep<60, 0>(p1, gt, win0, coord, objL, noObjC, clsL);
    winner_sweep<30, 1>(p2, gt, win1, coord, objL, noObjC, clsL);
    winner_sweep<15, 2>(p3, gt, win2, coord, objL, noObjC, clsL);

    coord *= 5.0f;                       // LAMBDA_COORD
    float no = (noObj + noObjC) * 0.5f;  // LAMBDA_NOOBJ

    __shared__ float sm[4][4];
    int lane = threadIdx.x & 63;
    int wid = threadIdx.x >> 6;
    coord = wave_red(coord);
    objL = wave_red(objL);
    no = wave_red(no);
    clsL = wave_red(clsL);
    if (lane == 0) { sm[wid][0] = coord; sm[wid][1] = objL; sm[wid][2] = no; sm[wid][3] = clsL; }
    __syncthreads();
    if (threadIdx.x < 4) {
        float a = sm[0][threadIdx.x] + sm[1][threadIdx.x] + sm[2][threadIdx.x] + sm[3][threadIdx.x];
        partials[(size_t)blockIdx.x * 4 + threadIdx.x] = a;  // distinct slots, no atomics
    }
}

// Single block: reduce MAIN_BLOCKS x 4 partials into the 5 outputs.
__global__ __launch_bounds__(256) void finalize_kernel(const float* __restrict__ partials,
                                                       float* __restrict__ out) {
    int lane = threadIdx.x & 63;
    int w = threadIdx.x >> 6;  // wave w reduces component w
    float s = 0.f;
    for (int i = lane; i < MAIN_BLOCKS; i += 64) s += partials[i * 4 + w];
    s = wave_red(s);
    __shared__ float sm[4];
    if (lane == 0) sm[w] = s;
    __syncthreads();
    if (threadIdx.x == 0) {
        out[0] = sm[0] + sm[1] + sm[2] + sm[3];
        out[1] = sm[0];  // coord
        out[2] = sm[1];  // objL
        out[3] = sm[2];  // noObjL
        out[4] = sm[3];  // clsL
    }
}

extern "C" void kernel_launch(void* const* d_in, const int* in_sizes, int n_in,
                              void* d_out, int out_size, void* d_ws, size_t ws_size,
                              hipStream_t stream) {
    const float* p1 = (const float*)d_in[0];  // (64,3,60,60,25)
    const float* p2 = (const float*)d_in[1];  // (64,3,30,30,25)
    const float* p3 = (const float*)d_in[2];  // (64,3,15,15,25)
    const float* gt = (const float*)d_in[3];  // (64,300,25)
    float* out = (float*)d_out;               // [total, coord, objL, noObjL, clsL]

    int* win0 = (int*)d_ws;
    int* win1 = win0 + N0;
    int* win2 = win1 + N1;
    float* partials = (float*)(win2 + N2);    // MAIN_BLOCKS*4 floats
    size_t winBytes = (size_t)NTOT * sizeof(int);

    (void)hipMemsetAsync(d_ws, 0xFF, winBytes, stream);  // winners = -1

    int nGT = BATCH * MGT;
    assign_kernel<<<(nGT + 255) / 256, 256, 0, stream>>>(gt, win0, win1, win2);

    main_kernel<<<MAIN_BLOCKS, 256, 0, stream>>>(
        (const f32x4*)p1, (const f32x4*)p2, (const f32x4*)p3,
        p1, p2, p3, gt, win0, win1, win2, partials);
    finalize_kernel<<<1, 256, 0, stream>>>(partials, out);
}

// Round 6
// 142.073 us; speedup vs baseline: 1.2151x; 1.2151x over previous
//
#include <hip/hip_runtime.h>

#define BATCH 64
#define MGT 300
#define NCLS 20
#define IMG 480.0f

#define N0 (BATCH * 3 * 60 * 60)   // 691200 cells
#define N1 (BATCH * 3 * 30 * 30)   // 172800
#define N2 (BATCH * 3 * 15 * 15)   //  43200
#define NTOT (N0 + N1 + N2)        // 907200

#define F1 (N0 * 25 / 4)           // float4 counts
#define F2 (N1 * 25 / 4)
#define F3 (N2 * 25 / 4)
#define FT (F1 + F2 + F3)          // 5,670,000

#define MAIN_BLOCKS 2048           // 8 blocks/CU
#define STRIDE (MAIN_BLOCKS * 256) // 524288 threads

typedef float f32x4 __attribute__((ext_vector_type(4)));

// Anchors: s0 (10,13),(16,30),(33,23); s1 (30,61),(62,45),(59,119); s2 (116,90),(156,198),(373,326)
__constant__ float c_aw[3][3] = {{10.f, 16.f, 33.f}, {30.f, 62.f, 59.f}, {116.f, 156.f, 373.f}};
__constant__ float c_ah[3][3] = {{13.f, 30.f, 23.f}, {61.f, 45.f, 119.f}, {90.f, 198.f, 326.f}};

__device__ __forceinline__ float wave_red(float v) {
    #pragma unroll
    for (int o = 32; o > 0; o >>= 1) v += __shfl_down(v, o, 64);
    return v;
}

// One thread per (b,m) GT: best anchor per scale; atomicMax(m) = last-write-wins scatter.
__global__ void assign_kernel(const float* __restrict__ gt,
                              int* __restrict__ win0, int* __restrict__ win1, int* __restrict__ win2) {
    int t = blockIdx.x * blockDim.x + threadIdx.x;
    if (t >= BATCH * MGT) return;
    int b = t / MGT;
    int m = t - b * MGT;
    const float* g = gt + (size_t)t * 25;
    if (!(g[4] > 0.5f)) return;
    float mx = g[0], my = g[1];
    float w = g[2] * IMG, h = g[3] * IMG;
    float wh = w * h;

    const int Gs[3] = {60, 30, 15};
    int* wins[3] = {win0, win1, win2};
    #pragma unroll
    for (int s = 0; s < 3; ++s) {
        int G = Gs[s];
        int gx = min(max((int)floorf(mx * (float)G), 0), G - 1);
        int gy = min(max((int)floorf(my * (float)G), 0), G - 1);
        float bestR = -1.0f;
        int best = 0;
        #pragma unroll
        for (int a = 0; a < 3; ++a) {
            float aw = c_aw[s][a], ah = c_ah[s][a];
            float inter = fminf(w, aw) * fminf(h, ah);
            float uni = wh + aw * ah - inter;
            float r = inter / (uni + 1e-16f);
            if (r > bestR) { bestR = r; best = a; }  // strict > : argmax first-wins
        }
        int cell = ((b * 3 + best) * G + gy) * G + gx;
        atomicMax(&wins[s][cell], m);
    }
}

// Branchless-ish 3-tensor address select; plain cached load (R5 lesson: nt
// bypassed the L2/L3-resident restored inputs and forced HBM fetches).
__device__ __forceinline__ f32x4 ld_at(int i,
                                       const f32x4* __restrict__ p1v,
                                       const f32x4* __restrict__ p2v,
                                       const f32x4* __restrict__ p3v) {
    const f32x4* base = p1v;
    int li = i;
    if (i >= F1 + F2)      { base = p3v; li = i - (F1 + F2); }
    else if (i >= F1)      { base = p2v; li = i - F1; }
    return base[li];
}

// bce(conf, 0) contribution if this float4 holds a conf element ((4i+j)%25==4).
__device__ __forceinline__ float conf_term(f32x4 v, int i) {
    unsigned r = (4u * (unsigned)i) % 25u;    // const-divisor -> magic mul
    unsigned j0 = (29u - r) % 25u;            // (4 - r) mod 25
    float t = 0.f;
    if (j0 < 4u) {
        float p = v[j0];
        t = (p < 1.0f) ? fmaxf(logf(1.0f - p), -100.0f) : -100.0f;
    }
    return t;   // caller does acc -= t
}

// Winner cells only (~1-3%): coord/obj/cls + noObj correction. Compile-time G.
template <int G, int S>
__device__ __forceinline__ void winner_sweep(const float* __restrict__ pred,
                                             const float* __restrict__ gt,
                                             const int* __restrict__ win,
                                             float& coord, float& objL, float& noObjC, float& clsL) {
    const int n = BATCH * 3 * G * G;
    for (int c = blockIdx.x * blockDim.x + threadIdx.x; c < n; c += gridDim.x * blockDim.x) {
        int m = win[c];
        if (m < 0) continue;
        const float* p = pred + (size_t)c * 25;
        float pconf = p[4];
        // stream phase added -lq for this cell; true noObj term is 0 -> add it back
        float lq = (pconf < 1.0f) ? fmaxf(logf(1.0f - pconf), -100.0f) : -100.0f;
        noObjC += lq;

        int gx = c % G;
        int t1 = c / G;
        int gy = t1 % G;
        int t2 = t1 / G;
        int a = t2 % 3;
        int b = t2 / 3;
        const float* g = gt + ((size_t)b * MGT + m) * 25;
        float w = g[2] * IMG, h = g[3] * IMG;
        float tx = g[0] * (float)G - (float)gx;
        float ty = g[1] * (float)G - (float)gy;
        float tw = logf(w / c_aw[S][a] + 1e-16f);
        float th = logf(h / c_ah[S][a] + 1e-16f);
        float dx = p[0] - tx, dy = p[1] - ty, dw = p[2] - tw, dh = p[3] - th;
        coord += dx * dx + dy * dy + dw * dw + dh * dh;
        float lp = (pconf > 0.0f) ? fmaxf(logf(pconf), -100.0f) : -100.0f;
        objL -= lp;
        #pragma unroll
        for (int k = 0; k < NCLS; ++k) {
            float pc = p[5 + k], tc = g[5 + k];
            float lpk = (pc > 0.0f) ? fmaxf(logf(pc), -100.0f) : -100.0f;
            float lqk = (pc < 1.0f) ? fmaxf(logf(1.0f - pc), -100.0f) : -100.0f;
            clsL -= tc * lpk + (1.0f - tc) * lqk;
        }
    }
}

// Phase A: coalesced stream over ALL pred floats with a 4-deep explicit load
// pipeline (R5 lesson: load->use->load->use left ~1 outstanding load; 4
// independent loads issue before any consume). Phase B: winner sweeps.
__global__ __launch_bounds__(256) void main_kernel(
        const f32x4* __restrict__ p1v, const f32x4* __restrict__ p2v, const f32x4* __restrict__ p3v,
        const float* __restrict__ p1, const float* __restrict__ p2, const float* __restrict__ p3,
        const float* __restrict__ gt,
        const int* __restrict__ win0, const int* __restrict__ win1, const int* __restrict__ win2,
        float* __restrict__ partials) {
    float noObj = 0.f;
    int i = blockIdx.x * blockDim.x + threadIdx.x;

    // 4-deep pipeline: loads first (independent), then consumes
    for (; i + 3 * STRIDE < FT; i += 4 * STRIDE) {
        f32x4 v0 = ld_at(i,              p1v, p2v, p3v);
        f32x4 v1 = ld_at(i + STRIDE,     p1v, p2v, p3v);
        f32x4 v2 = ld_at(i + 2 * STRIDE, p1v, p2v, p3v);
        f32x4 v3 = ld_at(i + 3 * STRIDE, p1v, p2v, p3v);
        noObj -= conf_term(v0, i) + conf_term(v1, i + STRIDE)
               + conf_term(v2, i + 2 * STRIDE) + conf_term(v3, i + 3 * STRIDE);
    }
    // 2-deep tail
    for (; i + STRIDE < FT; i += 2 * STRIDE) {
        f32x4 v0 = ld_at(i,          p1v, p2v, p3v);
        f32x4 v1 = ld_at(i + STRIDE, p1v, p2v, p3v);
        noObj -= conf_term(v0, i) + conf_term(v1, i + STRIDE);
    }
    if (i < FT) {
        noObj -= conf_term(ld_at(i, p1v, p2v, p3v), i);
    }

    float coord = 0.f, objL = 0.f, noObjC = 0.f, clsL = 0.f;
    winner_sweep<60, 0>(p1, gt, win0, coord, objL, noObjC, clsL);
    winner_sweep<30, 1>(p2, gt, win1, coord, objL, noObjC, clsL);
    winner_sweep<15, 2>(p3, gt, win2, coord, objL, noObjC, clsL);

    coord *= 5.0f;                       // LAMBDA_COORD
    float no = (noObj + noObjC) * 0.5f;  // LAMBDA_NOOBJ

    __shared__ float sm[4][4];
    int lane = threadIdx.x & 63;
    int wid = threadIdx.x >> 6;
    coord = wave_red(coord);
    objL = wave_red(objL);
    no = wave_red(no);
    clsL = wave_red(clsL);
    if (lane == 0) { sm[wid][0] = coord; sm[wid][1] = objL; sm[wid][2] = no; sm[wid][3] = clsL; }
    __syncthreads();
    if (threadIdx.x < 4) {
        float a = sm[0][threadIdx.x] + sm[1][threadIdx.x] + sm[2][threadIdx.x] + sm[3][threadIdx.x];
        partials[(size_t)blockIdx.x * 4 + threadIdx.x] = a;  // distinct slots, no atomics
    }
}

// Single block: reduce MAIN_BLOCKS x 4 partials into the 5 outputs.
__global__ __launch_bounds__(256) void finalize_kernel(const float* __restrict__ partials,
                                                       float* __restrict__ out) {
    int lane = threadIdx.x & 63;
    int w = threadIdx.x >> 6;  // wave w reduces component w
    float s = 0.f;
    for (int i = lane; i < MAIN_BLOCKS; i += 64) s += partials[i * 4 + w];
    s = wave_red(s);
    __shared__ float sm[4];
    if (lane == 0) sm[w] = s;
    __syncthreads();
    if (threadIdx.x == 0) {
        out[0] = sm[0] + sm[1] + sm[2] + sm[3];
        out[1] = sm[0];  // coord
        out[2] = sm[1];  // objL
        out[3] = sm[2];  // noObjL
        out[4] = sm[3];  // clsL
    }
}

extern "C" void kernel_launch(void* const* d_in, const int* in_sizes, int n_in,
                              void* d_out, int out_size, void* d_ws, size_t ws_size,
                              hipStream_t stream) {
    const float* p1 = (const float*)d_in[0];  // (64,3,60,60,25)
    const float* p2 = (const float*)d_in[1];  // (64,3,30,30,25)
    const float* p3 = (const float*)d_in[2];  // (64,3,15,15,25)
    const float* gt = (const float*)d_in[3];  // (64,300,25)
    float* out = (float*)d_out;               // [total, coord, objL, noObjL, clsL]

    int* win0 = (int*)d_ws;
    int* win1 = win0 + N0;
    int* win2 = win1 + N1;
    float* partials = (float*)(win2 + N2);    // MAIN_BLOCKS*4 floats
    size_t winBytes = (size_t)NTOT * sizeof(int);

    (void)hipMemsetAsync(d_ws, 0xFF, winBytes, stream);  // winners = -1

    int nGT = BATCH * MGT;
    assign_kernel<<<(nGT + 255) / 256, 256, 0, stream>>>(gt, win0, win1, win2);

    main_kernel<<<MAIN_BLOCKS, 256, 0, stream>>>(
        (const f32x4*)p1, (const f32x4*)p2, (const f32x4*)p3,
        p1, p2, p3, gt, win0, win1, win2, partials);
    finalize_kernel<<<1, 256, 0, stream>>>(partials, out);
}